// Round 1
// baseline (1228.950 us; speedup 1.0000x reference)
//
#include <hip/hip_runtime.h>

#define INPT 64
#define HID 128
#define NNODE 10000
#define K_NEIGH 16
#define BATCH 8
#define ROWS (BATCH * NNODE)   // 80000

// Y[r][j] = relu(sum_i X[r][i] * W[i][j] + bias[j])
// X: [ROWS, IN], W: [IN, HID] row-major, Y: [ROWS, HID]
template<int IN>
__global__ __launch_bounds__(HID) void embed_kernel(
    const float* __restrict__ X, const float* __restrict__ W,
    const float* __restrict__ bias, float* __restrict__ Y) {
    __shared__ float xs[IN];
    const int r = blockIdx.x;
    const int j = threadIdx.x;
    const float* xrow = X + (size_t)r * IN;
    if (j < IN) xs[j] = xrow[j];
    __syncthreads();
    float acc = bias[j];
#pragma unroll
    for (int i = 0; i < IN; ++i) acc += xs[i] * W[i * HID + j];
    Y[(size_t)r * HID + j] = fmaxf(acc, 0.f);
}

// For row (b,n):
//   aggr[:] = sum_k SE[b, sidx[n,k], :] + sum_k IE[b, iidx[n,k], :]
//   h[:]    = IE[b, n, :]
//   Y[b,n,j] = relu(bu[j] + sum_i aggr[i]*Wu[i,j] + sum_i h[i]*Wu[HID+i,j])
__global__ __launch_bounds__(HID) void update_kernel(
    const float* __restrict__ SE, const float* __restrict__ IE,
    const int* __restrict__ sidx, const int* __restrict__ iidx,
    const float* __restrict__ Wu, const float* __restrict__ bu,
    float* __restrict__ Y) {
    const int bn = blockIdx.x;            // 0 .. ROWS-1
    const int b = bn / NNODE;
    const int n = bn % NNODE;
    const int j = threadIdx.x;            // 0 .. 127

    __shared__ float aggr[HID];
    __shared__ float hs[HID];

    const size_t base = (size_t)b * NNODE * HID;
    float a = 0.f;
#pragma unroll
    for (int k = 0; k < K_NEIGH; ++k) {
        const int ns = sidx[n * K_NEIGH + k];
        const int ni = iidx[n * K_NEIGH + k];
        a += SE[base + (size_t)ns * HID + j];
        a += IE[base + (size_t)ni * HID + j];
    }
    aggr[j] = a;
    hs[j] = IE[base + (size_t)n * HID + j];
    __syncthreads();

    float acc = bu[j];
#pragma unroll
    for (int i = 0; i < HID; ++i) acc += aggr[i] * Wu[i * HID + j];
#pragma unroll
    for (int i = 0; i < HID; ++i) acc += hs[i] * Wu[(HID + i) * HID + j];
    Y[(size_t)bn * HID + j] = fmaxf(acc, 0.f);
}

extern "C" void kernel_launch(void* const* d_in, const int* in_sizes, int n_in,
                              void* d_out, int out_size, void* d_ws, size_t ws_size,
                              hipStream_t stream) {
    const float* state    = (const float*)d_in[0];
    const float* internal = (const float*)d_in[1];
    const int*   sidx     = (const int*)d_in[2];
    const int*   iidx     = (const int*)d_in[3];
    const float* W1  = (const float*)d_in[4];
    const float* b1  = (const float*)d_in[5];
    const float* W2  = (const float*)d_in[6];
    const float* b2  = (const float*)d_in[7];
    const float* Wu1 = (const float*)d_in[8];
    const float* bu1 = (const float*)d_in[9];
    const float* Wu2 = (const float*)d_in[10];
    const float* bu2 = (const float*)d_in[11];

    float* hu1 = (float*)d_out;                          // [ROWS, HID]
    float* hu2 = hu1 + (size_t)ROWS * HID;               // [ROWS, HID]

    // Workspace: two ping-pong buffers of [ROWS, HID] each (41 MB apiece).
    float* bufA = (float*)d_ws;                          // state_embed, later ie2
    float* bufB = bufA + (size_t)ROWS * HID;             // internal_embed, later se2

    dim3 blk(HID);
    dim3 grd(ROWS);

    // Layer-1 embeddings
    embed_kernel<INPT><<<grd, blk, 0, stream>>>(state,    W1, b1, bufA);  // state_embed
    embed_kernel<INPT><<<grd, blk, 0, stream>>>(internal, W1, b1, bufB);  // internal_embed

    // hu1 = relu(concat(aggr1, internal_embed) @ Wu1 + bu1)
    update_kernel<<<grd, blk, 0, stream>>>(bufA, bufB, sidx, iidx, Wu1, bu1, hu1);

    // se2 = relu(state_embed @ W2 + b2)   (reads bufA, writes bufB; internal_embed dead)
    embed_kernel<HID><<<grd, blk, 0, stream>>>(bufA, W2, b2, bufB);
    // ie2 = relu(hu1 @ W2 + b2)           (reads hu1, writes bufA; state_embed dead)
    embed_kernel<HID><<<grd, blk, 0, stream>>>(hu1, W2, b2, bufA);

    // hu2 = relu(concat(aggr2, ie2) @ Wu2 + bu2)  (SE=se2=bufB via sidx, IE=ie2=bufA via iidx)
    update_kernel<<<grd, blk, 0, stream>>>(bufB, bufA, sidx, iidx, Wu2, bu2, hu2);
}

// Round 2
// 354.760 us; speedup vs baseline: 3.4642x; 3.4642x over previous
//
#include <hip/hip_runtime.h>

#define HID 128
#define NNODE 10000
#define KN 16
#define ROWS 80000   // BATCH * NNODE

typedef __attribute__((ext_vector_type(8))) short short8;   // 8 bf16 (4 VGPRs)
typedef __attribute__((ext_vector_type(4))) float f32x4;

__device__ __forceinline__ unsigned short f2b(float f) {
    unsigned u = __float_as_uint(f);
    u += 0x7FFFu + ((u >> 16) & 1u);       // round-to-nearest-even
    return (unsigned short)(u >> 16);
}
__device__ __forceinline__ float b2f(unsigned short h) {
    return __uint_as_float(((unsigned)h) << 16);
}

// Wt[n][k] = bf16(W[k][n]);  W: [K][128] f32 row-major
template<int K>
__global__ __launch_bounds__(256) void wconv_kernel(
    const float* __restrict__ W, unsigned short* __restrict__ Wt) {
    const int idx = blockIdx.x * 256 + threadIdx.x;   // < K*128
    const int n = idx & 127;
    const int k = idx >> 7;
    Wt[n * K + k] = f2b(W[idx]);
}

// Y[r][j] = relu(A[r][:] @ W[:,j] + bias[j]) in bf16 MFMA.
// A: [ROWS][K] (f32 if AF32 else bf16), Wt: [128][K] bf16 (pre-transposed), Yb: [ROWS][128] bf16
template<int K, bool AF32>
__global__ __launch_bounds__(256) void embed_mfma(
    const void* __restrict__ Ain, const unsigned short* __restrict__ Wt,
    const float* __restrict__ bias, unsigned short* __restrict__ Yb) {
    const int wave = threadIdx.x >> 6, lane = threadIdx.x & 63;
    const int lrow = lane & 15, lk = lane >> 4;
    const int m0 = blockIdx.x * 64 + wave * 16;       // this wave's 16-row strip
    const int arow = m0 + lrow;

    short8 a[K / 32];
    if constexpr (AF32) {
        const float* A = (const float*)Ain;
#pragma unroll
        for (int kt = 0; kt < K / 32; ++kt) {
            const float* p = A + (size_t)arow * K + kt * 32 + lk * 8;
            f32x4 f0 = *(const f32x4*)p;
            f32x4 f1 = *(const f32x4*)(p + 4);
            short8 v;
#pragma unroll
            for (int e = 0; e < 4; ++e) { v[e] = (short)f2b(f0[e]); v[4 + e] = (short)f2b(f1[e]); }
            a[kt] = v;
        }
    } else {
        const unsigned short* A = (const unsigned short*)Ain;
#pragma unroll
        for (int kt = 0; kt < K / 32; ++kt)
            a[kt] = *(const short8*)(A + (size_t)arow * K + kt * 32 + lk * 8);
    }

#pragma unroll
    for (int nt = 0; nt < 8; ++nt) {
        f32x4 acc = {0.f, 0.f, 0.f, 0.f};
#pragma unroll
        for (int kt = 0; kt < K / 32; ++kt) {
            short8 b = *(const short8*)(Wt + (nt * 16 + lrow) * K + kt * 32 + lk * 8);
            acc = __builtin_amdgcn_mfma_f32_16x16x32_bf16(a[kt], b, acc, 0, 0, 0);
        }
        const int ocol = nt * 16 + lrow;
        const float bv = bias[ocol];
#pragma unroll
        for (int j = 0; j < 4; ++j) {
            const int orow = m0 + lk * 4 + j;
            float v = acc[j] + bv;
            v = v > 0.f ? v : 0.f;
            Yb[(size_t)orow * HID + ocol] = f2b(v);
        }
    }
}

// Per row bn: aggr = sum_k SE[gather sidx] + sum_k IE[gather iidx]  (f32 accum)
// A = [aggr | IE[bn]]  (K=256, bf16, LDS w/ XOR swizzle), Y = relu(A @ Wut^T + bu)
__global__ __launch_bounds__(256) void update_mfma(
    const unsigned short* __restrict__ SE, const unsigned short* __restrict__ IE,
    const int* __restrict__ sidx, const int* __restrict__ iidx,
    const unsigned short* __restrict__ Wut, const float* __restrict__ bu,
    float* __restrict__ Yf, unsigned short* __restrict__ Yb, int writeb) {
    __shared__ __align__(16) unsigned short At[64 * 256];   // 32 KB, swizzled
    char* Ab = (char*)At;                                    // row stride 512 B
    const int t = threadIdx.x;

    {   // ---- Phase A: gather + aggregate + stage (4 threads per row, 32 cols each)
        const int r = t >> 2, p = t & 3;
        const int bn = blockIdx.x * 64 + r;
        const int b = bn / NNODE;
        const int n = bn - b * NNODE;
        const size_t base = (size_t)b * NNODE * HID;
        const int coff = p * 32;

        float acc[32];
#pragma unroll
        for (int c = 0; c < 32; ++c) acc[c] = 0.f;

#pragma unroll
        for (int k = 0; k < KN; ++k) {
            const int ns = sidx[n * KN + k];
            const unsigned short* s = SE + base + (size_t)ns * HID + coff;
#pragma unroll
            for (int q = 0; q < 4; ++q) {
                short8 v = *(const short8*)(s + q * 8);
#pragma unroll
                for (int e = 0; e < 8; ++e) acc[q * 8 + e] += b2f((unsigned short)v[e]);
            }
        }
#pragma unroll
        for (int k = 0; k < KN; ++k) {
            const int ni = iidx[n * KN + k];
            const unsigned short* s = IE + base + (size_t)ni * HID + coff;
#pragma unroll
            for (int q = 0; q < 4; ++q) {
                short8 v = *(const short8*)(s + q * 8);
#pragma unroll
                for (int e = 0; e < 8; ++e) acc[q * 8 + e] += b2f((unsigned short)v[e]);
            }
        }
        // aggr -> A[:, 0:128]
#pragma unroll
        for (int q = 0; q < 4; ++q) {
            short8 v;
#pragma unroll
            for (int e = 0; e < 8; ++e) v[e] = (short)f2b(acc[q * 8 + e]);
            const int kbyte = coff * 2 + q * 16;
            *(short8*)(Ab + r * 512 + (kbyte ^ ((r & 7) << 4))) = v;
        }
        // h = IE[bn] -> A[:, 128:256] (already bf16, copy)
        const unsigned short* hs = IE + (size_t)bn * HID + coff;
#pragma unroll
        for (int q = 0; q < 4; ++q) {
            short8 v = *(const short8*)(hs + q * 8);
            const int kbyte = 256 + coff * 2 + q * 16;
            *(short8*)(Ab + r * 512 + (kbyte ^ ((r & 7) << 4))) = v;
        }
    }
    __syncthreads();

    // ---- Phase B: GEMM, one wave = 16 rows x 128 cols, K=256
    const int wave = t >> 6, lane = t & 63;
    const int lrow = lane & 15, lk = lane >> 4;
    const int row = wave * 16 + lrow;

    short8 a[8];
#pragma unroll
    for (int kt = 0; kt < 8; ++kt) {
        const int kbyte = kt * 64 + lk * 16;
        a[kt] = *(const short8*)(Ab + row * 512 + (kbyte ^ ((row & 7) << 4)));
    }
#pragma unroll
    for (int nt = 0; nt < 8; ++nt) {
        f32x4 acc = {0.f, 0.f, 0.f, 0.f};
#pragma unroll
        for (int kt = 0; kt < 8; ++kt) {
            short8 b = *(const short8*)(Wut + (nt * 16 + lrow) * 256 + kt * 32 + lk * 8);
            acc = __builtin_amdgcn_mfma_f32_16x16x32_bf16(a[kt], b, acc, 0, 0, 0);
        }
        const int ocol = nt * 16 + lrow;
        const float bv = bu[ocol];
#pragma unroll
        for (int j = 0; j < 4; ++j) {
            const int orow = blockIdx.x * 64 + wave * 16 + lk * 4 + j;
            float v = acc[j] + bv;
            v = v > 0.f ? v : 0.f;
            Yf[(size_t)orow * HID + ocol] = v;
            if (writeb) Yb[(size_t)orow * HID + ocol] = f2b(v);
        }
    }
}

extern "C" void kernel_launch(void* const* d_in, const int* in_sizes, int n_in,
                              void* d_out, int out_size, void* d_ws, size_t ws_size,
                              hipStream_t stream) {
    const float* state    = (const float*)d_in[0];
    const float* internal = (const float*)d_in[1];
    const int*   sidx     = (const int*)d_in[2];
    const int*   iidx     = (const int*)d_in[3];
    const float* W1  = (const float*)d_in[4];
    const float* b1  = (const float*)d_in[5];
    const float* W2  = (const float*)d_in[6];
    const float* b2  = (const float*)d_in[7];
    const float* Wu1 = (const float*)d_in[8];
    const float* bu1 = (const float*)d_in[9];
    const float* Wu2 = (const float*)d_in[10];
    const float* bu2 = (const float*)d_in[11];

    float* hu1 = (float*)d_out;
    float* hu2 = hu1 + (size_t)ROWS * HID;

    unsigned short* W1t  = (unsigned short*)d_ws;          // [128][64]
    unsigned short* W2t  = W1t  + 64 * 128;                // [128][128]
    unsigned short* Wu1t = W2t  + 128 * 128;               // [128][256]
    unsigned short* Wu2t = Wu1t + 256 * 128;               // [128][256]
    unsigned short* bufA = Wu2t + 256 * 128;               // [ROWS][128] bf16
    unsigned short* bufB = bufA + (size_t)ROWS * HID;
    unsigned short* bufC = bufB + (size_t)ROWS * HID;

    dim3 blk(256);
    dim3 grd(ROWS / 64);   // 1250

    wconv_kernel<64> <<<32,  blk, 0, stream>>>(W1,  W1t);
    wconv_kernel<128><<<64,  blk, 0, stream>>>(W2,  W2t);
    wconv_kernel<256><<<128, blk, 0, stream>>>(Wu1, Wu1t);
    wconv_kernel<256><<<128, blk, 0, stream>>>(Wu2, Wu2t);

    // layer-1 embeddings (bf16 out)
    embed_mfma<64, true><<<grd, blk, 0, stream>>>(state,    W1t, b1, bufA);  // SE1
    embed_mfma<64, true><<<grd, blk, 0, stream>>>(internal, W1t, b1, bufB);  // IE1

    // hu1 = relu([aggr1 | IE1] @ Wu1 + bu1) -> f32 d_out + bf16 bufC
    update_mfma<<<grd, blk, 0, stream>>>(bufA, bufB, sidx, iidx, Wu1t, bu1, hu1, bufC, 1);

    // se2 = relu(SE1 @ W2 + b2)  (IE1 dead -> bufB)
    embed_mfma<128, false><<<grd, blk, 0, stream>>>(bufA, W2t, b2, bufB);
    // ie2 = relu(hu1 @ W2 + b2)  (SE1 dead -> bufA)
    embed_mfma<128, false><<<grd, blk, 0, stream>>>(bufC, W2t, b2, bufA);

    // hu2 = relu([aggr2 | ie2] @ Wu2 + bu2) -> f32 d_out
    update_mfma<<<grd, blk, 0, stream>>>(bufB, bufA, sidx, iidx, Wu2t, bu2, hu2, nullptr, 0);
}

// Round 3
// 252.966 us; speedup vs baseline: 4.8582x; 1.4024x over previous
//
#include <hip/hip_runtime.h>

#define HID 128
#define NNODE 10000
#define KN 16
#define ROWS 80000   // BATCH * NNODE
#define UROWS 32     // rows per update block

typedef __attribute__((ext_vector_type(8))) short short8;   // 8 bf16 (4 VGPRs)
typedef __attribute__((ext_vector_type(4))) float f32x4;

__device__ __forceinline__ unsigned short f2b(float f) {
    unsigned u = __float_as_uint(f);
    u += 0x7FFFu + ((u >> 16) & 1u);       // round-to-nearest-even
    return (unsigned short)(u >> 16);
}
__device__ __forceinline__ float b2f(unsigned short h) {
    return __uint_as_float(((unsigned)h) << 16);
}

// All four weight transposes+converts in one launch.
// W1[64][128]->W1t[128][64]; W2[128][128]->W2t[128][128]; Wu*[256][128]->Wu*t[128][256]
__global__ __launch_bounds__(256) void wconv_all(
    const float* __restrict__ W1, const float* __restrict__ W2,
    const float* __restrict__ Wu1, const float* __restrict__ Wu2,
    unsigned short* __restrict__ W1t, unsigned short* __restrict__ W2t,
    unsigned short* __restrict__ Wu1t, unsigned short* __restrict__ Wu2t) {
    int idx = blockIdx.x * 256 + threadIdx.x;   // < 90112
    const float* W; unsigned short* Wt; int K; int off;
    if (idx < 8192)       { W = W1;  Wt = W1t;  K = 64;  off = idx; }
    else if (idx < 24576) { W = W2;  Wt = W2t;  K = 128; off = idx - 8192; }
    else if (idx < 57344) { W = Wu1; Wt = Wu1t; K = 256; off = idx - 24576; }
    else                  { W = Wu2; Wt = Wu2t; K = 256; off = idx - 57344; }
    int n = off & 127, k = off >> 7;
    Wt[n * K + k] = f2b(W[off]);
}

// Y[r][j] = relu(A[r][:] @ W[:,j] + bias[j]) via bf16 MFMA.
// Two independent (A,Y) pairs in one launch (grid = 2*1250).
template<int K, bool AF32>
__global__ __launch_bounds__(256) void embed_mfma(
    const void* __restrict__ A0, const void* __restrict__ A1,
    const unsigned short* __restrict__ Wt, const float* __restrict__ bias,
    unsigned short* __restrict__ Y0, unsigned short* __restrict__ Y1) {
    int g = blockIdx.x;
    const void* Ain = A0; unsigned short* Yb = Y0;
    if (g >= 1250) { Ain = A1; Yb = Y1; g -= 1250; }

    const int wave = threadIdx.x >> 6, lane = threadIdx.x & 63;
    const int lrow = lane & 15, lk = lane >> 4;
    const int m0 = g * 64 + wave * 16;
    const int arow = m0 + lrow;

    short8 a[K / 32];
    if constexpr (AF32) {
        const float* A = (const float*)Ain;
#pragma unroll
        for (int kt = 0; kt < K / 32; ++kt) {
            const float* p = A + (size_t)arow * K + kt * 32 + lk * 8;
            f32x4 f0 = *(const f32x4*)p;
            f32x4 f1 = *(const f32x4*)(p + 4);
            short8 v;
#pragma unroll
            for (int e = 0; e < 4; ++e) { v[e] = (short)f2b(f0[e]); v[4 + e] = (short)f2b(f1[e]); }
            a[kt] = v;
        }
    } else {
        const unsigned short* A = (const unsigned short*)Ain;
#pragma unroll
        for (int kt = 0; kt < K / 32; ++kt)
            a[kt] = *(const short8*)(A + (size_t)arow * K + kt * 32 + lk * 8);
    }

#pragma unroll
    for (int nt = 0; nt < 8; ++nt) {
        f32x4 acc = {0.f, 0.f, 0.f, 0.f};
#pragma unroll
        for (int kt = 0; kt < K / 32; ++kt) {
            short8 b = *(const short8*)(Wt + (nt * 16 + lrow) * K + kt * 32 + lk * 8);
            acc = __builtin_amdgcn_mfma_f32_16x16x32_bf16(a[kt], b, acc, 0, 0, 0);
        }
        const int ocol = nt * 16 + lrow;
        const float bv = bias[ocol];
#pragma unroll
        for (int j = 0; j < 4; ++j) {
            const int orow = m0 + lk * 4 + j;
            float v = acc[j] + bv;
            v = v > 0.f ? v : 0.f;
            Yb[(size_t)orow * HID + ocol] = f2b(v);
        }
    }
}

// grid = 8 * 313; b = bid&7 (XCD<->batch affinity), 32 rows per block.
// Phase A: 16 threads/row gather+aggregate (1x16B indep load per gather).
// Phase B: 8 waves, wave w -> rows (w&1)*16, cols (w>>1)*32; K=256 bf16 MFMA.
__global__ __launch_bounds__(512) void update_mfma(
    const unsigned short* __restrict__ SE, const unsigned short* __restrict__ IE,
    const int* __restrict__ sidx, const int* __restrict__ iidx,
    const unsigned short* __restrict__ Wut, const float* __restrict__ bu,
    float* __restrict__ Yf, unsigned short* __restrict__ Yb, int writeb) {
    __shared__ __align__(16) unsigned short At[UROWS * 256];   // 16 KB, XOR-swizzled rows
    __shared__ int sh_idx[32][UROWS];                           // [neighbor][row], 4 KB
    char* Ab = (char*)At;
    const int t = threadIdx.x;
    const int b = blockIdx.x & 7;
    const int n0 = (blockIdx.x >> 3) * UROWS;                   // 0..9984
    const size_t base = (size_t)b * NNODE * HID;

    // ---- stage indices: element e -> row r=e>>5, neighbor k=e&31
#pragma unroll
    for (int h = 0; h < 2; ++h) {
        const int e = t + h * 512;
        const int r = e >> 5, k = e & 31;
        const int nr = n0 + r < NNODE ? n0 + r : NNODE - 1;
        sh_idx[k][r] = (k < KN) ? sidx[nr * KN + k] : iidx[nr * KN + (k - KN)];
    }
    __syncthreads();

    {   // ---- Phase A: gather + aggregate
        const int r = t >> 4;            // 0..31
        const int p = t & 15;            // 0..15
        const int col0 = p * 8;
        const int nr = n0 + r < NNODE ? n0 + r : NNODE - 1;

        float acc[8];
#pragma unroll
        for (int e = 0; e < 8; ++e) acc[e] = 0.f;

#pragma unroll
        for (int k = 0; k < KN; ++k) {
            const int ns = sh_idx[k][r];
            short8 v = *(const short8*)(SE + base + (size_t)ns * HID + col0);
#pragma unroll
            for (int e = 0; e < 8; ++e) acc[e] += b2f((unsigned short)v[e]);
        }
#pragma unroll
        for (int k = 0; k < KN; ++k) {
            const int ni = sh_idx[KN + k][r];
            short8 v = *(const short8*)(IE + base + (size_t)ni * HID + col0);
#pragma unroll
            for (int e = 0; e < 8; ++e) acc[e] += b2f((unsigned short)v[e]);
        }
        short8 v;
#pragma unroll
        for (int e = 0; e < 8; ++e) v[e] = (short)f2b(acc[e]);
        *(short8*)(Ab + r * 512 + ((col0 * 2) ^ ((r & 7) << 4))) = v;
        // h = IE[b, nr, :] -> A[:, 128:256]
        short8 hv = *(const short8*)(IE + base + (size_t)nr * HID + col0);
        *(short8*)(Ab + r * 512 + ((256 + col0 * 2) ^ ((r & 7) << 4))) = hv;
    }
    __syncthreads();

    // ---- Phase B: [32 x 256] @ [256 x 128]
    const int wave = t >> 6, lane = t & 63;
    const int lrow = lane & 15, lk = lane >> 4;
    const int rowg = wave & 1, colg = wave >> 1;
    const int row = rowg * 16 + lrow;

    short8 a[8];
#pragma unroll
    for (int kt = 0; kt < 8; ++kt)
        a[kt] = *(const short8*)(Ab + row * 512 + ((kt * 64 + lk * 16) ^ ((row & 7) << 4)));

#pragma unroll
    for (int nt2 = 0; nt2 < 2; ++nt2) {
        const int nt = colg * 2 + nt2;
        f32x4 acc = {0.f, 0.f, 0.f, 0.f};
#pragma unroll
        for (int kt = 0; kt < 8; ++kt) {
            short8 bb = *(const short8*)(Wut + (nt * 16 + lrow) * 256 + kt * 32 + lk * 8);
            acc = __builtin_amdgcn_mfma_f32_16x16x32_bf16(a[kt], bb, acc, 0, 0, 0);
        }
        const int ocol = nt * 16 + lrow;
        const float bv = bu[ocol];
#pragma unroll
        for (int j = 0; j < 4; ++j) {
            const int rr = rowg * 16 + lk * 4 + j;
            const int n_o = n0 + rr;
            if (n_o < NNODE) {
                const size_t orow = (size_t)b * NNODE + n_o;
                float vv = acc[j] + bv;
                vv = vv > 0.f ? vv : 0.f;
                Yf[orow * HID + ocol] = vv;
                if (writeb) Yb[orow * HID + ocol] = f2b(vv);
            }
        }
    }
}

extern "C" void kernel_launch(void* const* d_in, const int* in_sizes, int n_in,
                              void* d_out, int out_size, void* d_ws, size_t ws_size,
                              hipStream_t stream) {
    const float* state    = (const float*)d_in[0];
    const float* internal = (const float*)d_in[1];
    const int*   sidx     = (const int*)d_in[2];
    const int*   iidx     = (const int*)d_in[3];
    const float* W1  = (const float*)d_in[4];
    const float* b1  = (const float*)d_in[5];
    const float* W2  = (const float*)d_in[6];
    const float* b2  = (const float*)d_in[7];
    const float* Wu1 = (const float*)d_in[8];
    const float* bu1 = (const float*)d_in[9];
    const float* Wu2 = (const float*)d_in[10];
    const float* bu2 = (const float*)d_in[11];

    float* hu1 = (float*)d_out;
    float* hu2 = hu1 + (size_t)ROWS * HID;

    unsigned short* W1t  = (unsigned short*)d_ws;          // [128][64]
    unsigned short* W2t  = W1t  + 64 * 128;                // [128][128]
    unsigned short* Wu1t = W2t  + 128 * 128;               // [128][256]
    unsigned short* Wu2t = Wu1t + 256 * 128;               // [128][256]
    unsigned short* bufA = Wu2t + 256 * 128;               // [ROWS][128] bf16
    unsigned short* bufB = bufA + (size_t)ROWS * HID;
    unsigned short* bufC = bufB + (size_t)ROWS * HID;

    dim3 b256(256), b512(512);

    wconv_all<<<352, b256, 0, stream>>>(W1, W2, Wu1, Wu2, W1t, W2t, Wu1t, Wu2t);

    // layer-1 embeddings: SE1 -> bufA, IE1 -> bufB (one launch)
    embed_mfma<64, true><<<2500, b256, 0, stream>>>(state, internal, W1t, b1, bufA, bufB);

    // hu1 = relu([aggr1 | IE1] @ Wu1 + bu1) -> f32 d_out + bf16 bufC
    update_mfma<<<8 * 313, b512, 0, stream>>>(bufA, bufB, sidx, iidx, Wu1t, bu1, hu1, bufC, 1);

    // se2 = relu(SE1 @ W2 + b2): bufA -> bufB (IE1 dead after update1)
    embed_mfma<128, false><<<1250, b256, 0, stream>>>(bufA, nullptr, W2t, b2, bufB, nullptr);
    // ie2 = relu(hu1 @ W2 + b2): bufC -> bufA (SE1 dead after se2 launch completes)
    embed_mfma<128, false><<<1250, b256, 0, stream>>>(bufC, nullptr, W2t, b2, bufA, nullptr);

    // hu2 = relu([aggr2 | ie2] @ Wu2 + bu2) -> f32 d_out
    update_mfma<<<8 * 313, b512, 0, stream>>>(bufB, bufA, sidx, iidx, Wu2t, bu2, hu2, nullptr, 0);
}

// Round 4
// 244.878 us; speedup vs baseline: 5.0186x; 1.0330x over previous
//
#include <hip/hip_runtime.h>

#define HID 128
#define NNODE 10000
#define KN 16
#define ROWS 80000   // BATCH * NNODE
#define UROWS 32     // rows per update block

typedef __attribute__((ext_vector_type(8))) short short8;   // 8 bf16 (4 VGPRs)
typedef __attribute__((ext_vector_type(4))) float f32x4;
typedef __attribute__((ext_vector_type(2))) float f32x2;
typedef __attribute__((ext_vector_type(4))) int i32x4;
typedef __attribute__((ext_vector_type(4))) unsigned int u32x4;

__device__ __forceinline__ unsigned short f2b(float f) {
    unsigned u = __float_as_uint(f);
    u += 0x7FFFu + ((u >> 16) & 1u);       // round-to-nearest-even
    return (unsigned short)(u >> 16);
}

// All four weight transposes+converts in one launch.
__global__ __launch_bounds__(256) void wconv_all(
    const float* __restrict__ W1, const float* __restrict__ W2,
    const float* __restrict__ Wu1, const float* __restrict__ Wu2,
    unsigned short* __restrict__ W1t, unsigned short* __restrict__ W2t,
    unsigned short* __restrict__ Wu1t, unsigned short* __restrict__ Wu2t) {
    int idx = blockIdx.x * 256 + threadIdx.x;   // < 90112
    const float* W; unsigned short* Wt; int K; int off;
    if (idx < 8192)       { W = W1;  Wt = W1t;  K = 64;  off = idx; }
    else if (idx < 24576) { W = W2;  Wt = W2t;  K = 128; off = idx - 8192; }
    else if (idx < 57344) { W = Wu1; Wt = Wu1t; K = 256; off = idx - 24576; }
    else                  { W = Wu2; Wt = Wu2t; K = 256; off = idx - 57344; }
    int n = off & 127, k = off >> 7;
    Wt[n * K + k] = f2b(W[off]);
}

// Y[r][j] = relu(A[r][:] @ W[:,j] + bias[j]) via bf16 MFMA.
// Two independent (A,Y) pairs in one launch (grid = 2*1250 when A1 != null).
template<int K, bool AF32>
__global__ __launch_bounds__(256) void embed_mfma(
    const void* __restrict__ A0, const void* __restrict__ A1,
    const unsigned short* __restrict__ Wt, const float* __restrict__ bias,
    unsigned short* __restrict__ Y0, unsigned short* __restrict__ Y1) {
    int g = blockIdx.x;
    const void* Ain = A0; unsigned short* Yb = Y0;
    if (g >= 1250) { Ain = A1; Yb = Y1; g -= 1250; }

    const int wave = threadIdx.x >> 6, lane = threadIdx.x & 63;
    const int lrow = lane & 15, lk = lane >> 4;
    const int m0 = g * 64 + wave * 16;
    const int arow = m0 + lrow;

    short8 a[K / 32];
    if constexpr (AF32) {
        const float* A = (const float*)Ain;
#pragma unroll
        for (int kt = 0; kt < K / 32; ++kt) {
            const float* p = A + (size_t)arow * K + kt * 32 + lk * 8;
            f32x4 f0 = *(const f32x4*)p;
            f32x4 f1 = *(const f32x4*)(p + 4);
            short8 v;
#pragma unroll
            for (int e = 0; e < 4; ++e) { v[e] = (short)f2b(f0[e]); v[4 + e] = (short)f2b(f1[e]); }
            a[kt] = v;
        }
    } else {
        const unsigned short* A = (const unsigned short*)Ain;
#pragma unroll
        for (int kt = 0; kt < K / 32; ++kt)
            a[kt] = *(const short8*)(A + (size_t)arow * K + kt * 32 + lk * 8);
    }

#pragma unroll
    for (int nt = 0; nt < 8; ++nt) {
        f32x4 acc = {0.f, 0.f, 0.f, 0.f};
#pragma unroll
        for (int kt = 0; kt < K / 32; ++kt) {
            short8 b = *(const short8*)(Wt + (nt * 16 + lrow) * K + kt * 32 + lk * 8);
            acc = __builtin_amdgcn_mfma_f32_16x16x32_bf16(a[kt], b, acc, 0, 0, 0);
        }
        const int ocol = nt * 16 + lrow;
        const float bv = bias[ocol];
#pragma unroll
        for (int j = 0; j < 4; ++j) {
            const int orow = m0 + lk * 4 + j;
            float v = acc[j] + bv;
            v = v > 0.f ? v : 0.f;
            Yb[(size_t)orow * HID + ocol] = f2b(v);
        }
    }
}

// grid = 8*313; b = bid&7 (XCD<->batch affinity), 32 rows per block, 512 thr.
// Phase A: 16 thr/row; 16 deep-pipelined 16B gathers per tensor in registers.
// Phase B: 8 waves, K=256 bf16 MFMA.
__global__ __launch_bounds__(512, 4) void update_mfma(
    const unsigned short* __restrict__ SE, const unsigned short* __restrict__ IE,
    const int* __restrict__ sidx, const int* __restrict__ iidx,
    const unsigned short* __restrict__ Wut, const float* __restrict__ bu,
    float* __restrict__ Yf, unsigned short* __restrict__ Yb, int writeb) {
    __shared__ __align__(16) unsigned short At[UROWS * 256];   // 16 KB, XOR-swizzled rows
    __shared__ __align__(16) int sh_idx[UROWS][36];            // padded: conflict-free
    char* Ab = (char*)At;
    const int t = threadIdx.x;
    const int b = blockIdx.x & 7;
    const int n0 = (blockIdx.x >> 3) * UROWS;
    const size_t base = (size_t)b * NNODE * HID;

    // ---- stage indices: elem e -> row r=e>>5, slot k=e&31; [r][k] padded to 36
#pragma unroll
    for (int h = 0; h < 2; ++h) {
        const int e = t + h * 512;
        const int r = e >> 5, k = e & 31;
        const int nr = min(n0 + r, NNODE - 1);
        sh_idx[r][k] = (k < KN) ? sidx[nr * KN + k] : iidx[nr * KN + (k - KN)];
    }
    __syncthreads();

    {   // ---- Phase A: gather + aggregate (register-blocked, 16 loads in flight)
        const int r = t >> 4;            // 0..31
        const int p = t & 15;            // 0..15
        const int col0 = p * 8;
        const int nr = min(n0 + r, NNODE - 1);
        const unsigned short* Sb = SE + base + col0;
        const unsigned short* Ib = IE + base + col0;

        // h row: issue early so it's in flight during the gathers
        short8 hv = *(const short8*)(IE + base + (size_t)nr * HID + col0);

        f32x2 acc[4];
#pragma unroll
        for (int j = 0; j < 4; ++j) acc[j] = (f32x2){0.f, 0.f};

        u32x4 vals[16];
        i32x4 iv[4];

        // SE pass
#pragma unroll
        for (int q = 0; q < 4; ++q) iv[q] = *(const i32x4*)&sh_idx[r][q * 4];
#pragma unroll
        for (int q = 0; q < 4; ++q)
#pragma unroll
            for (int j = 0; j < 4; ++j)
                vals[q * 4 + j] = *(const u32x4*)(Sb + (size_t)iv[q][j] * HID);
#pragma unroll
        for (int k = 0; k < 16; ++k)
#pragma unroll
            for (int j = 0; j < 4; ++j) {
                const unsigned u = vals[k][j];
                f32x2 pr = {__uint_as_float(u << 16), __uint_as_float(u & 0xffff0000u)};
                acc[j] += pr;
            }

        // IE pass
#pragma unroll
        for (int q = 0; q < 4; ++q) iv[q] = *(const i32x4*)&sh_idx[r][16 + q * 4];
#pragma unroll
        for (int q = 0; q < 4; ++q)
#pragma unroll
            for (int j = 0; j < 4; ++j)
                vals[q * 4 + j] = *(const u32x4*)(Ib + (size_t)iv[q][j] * HID);
#pragma unroll
        for (int k = 0; k < 16; ++k)
#pragma unroll
            for (int j = 0; j < 4; ++j) {
                const unsigned u = vals[k][j];
                f32x2 pr = {__uint_as_float(u << 16), __uint_as_float(u & 0xffff0000u)};
                acc[j] += pr;
            }

        // aggr -> A[:, 0:128]
        short8 ov;
#pragma unroll
        for (int j = 0; j < 4; ++j) {
            ov[2 * j]     = (short)f2b(acc[j].x);
            ov[2 * j + 1] = (short)f2b(acc[j].y);
        }
        *(short8*)(Ab + r * 512 + ((col0 * 2) ^ ((r & 7) << 4))) = ov;
        // h = IE[b, nr, :] -> A[:, 128:256]
        *(short8*)(Ab + r * 512 + ((256 + col0 * 2) ^ ((r & 7) << 4))) = hv;
    }
    __syncthreads();

    // ---- Phase B: [32 x 256] @ [256 x 128]
    const int wave = t >> 6, lane = t & 63;
    const int lrow = lane & 15, lk = lane >> 4;
    const int rowg = wave & 1, colg = wave >> 1;
    const int row = rowg * 16 + lrow;

    short8 a[8];
#pragma unroll
    for (int kt = 0; kt < 8; ++kt)
        a[kt] = *(const short8*)(Ab + row * 512 + ((kt * 64 + lk * 16) ^ ((row & 7) << 4)));

#pragma unroll
    for (int nt2 = 0; nt2 < 2; ++nt2) {
        const int nt = colg * 2 + nt2;
        f32x4 acc = {0.f, 0.f, 0.f, 0.f};
#pragma unroll
        for (int kt = 0; kt < 8; ++kt) {
            short8 bb = *(const short8*)(Wut + (nt * 16 + lrow) * 256 + kt * 32 + lk * 8);
            acc = __builtin_amdgcn_mfma_f32_16x16x32_bf16(a[kt], bb, acc, 0, 0, 0);
        }
        const int ocol = nt * 16 + lrow;
        const float bv = bu[ocol];
#pragma unroll
        for (int j = 0; j < 4; ++j) {
            const int rr = rowg * 16 + lk * 4 + j;
            const int n_o = n0 + rr;
            if (n_o < NNODE) {
                const size_t orow = (size_t)b * NNODE + n_o;
                float vv = acc[j] + bv;
                vv = vv > 0.f ? vv : 0.f;
                Yf[orow * HID + ocol] = vv;
                if (writeb) Yb[orow * HID + ocol] = f2b(vv);
            }
        }
    }
}

extern "C" void kernel_launch(void* const* d_in, const int* in_sizes, int n_in,
                              void* d_out, int out_size, void* d_ws, size_t ws_size,
                              hipStream_t stream) {
    const float* state    = (const float*)d_in[0];
    const float* internal = (const float*)d_in[1];
    const int*   sidx     = (const int*)d_in[2];
    const int*   iidx     = (const int*)d_in[3];
    const float* W1  = (const float*)d_in[4];
    const float* b1  = (const float*)d_in[5];
    const float* W2  = (const float*)d_in[6];
    const float* b2  = (const float*)d_in[7];
    const float* Wu1 = (const float*)d_in[8];
    const float* bu1 = (const float*)d_in[9];
    const float* Wu2 = (const float*)d_in[10];
    const float* bu2 = (const float*)d_in[11];

    float* hu1 = (float*)d_out;
    float* hu2 = hu1 + (size_t)ROWS * HID;

    unsigned short* W1t  = (unsigned short*)d_ws;          // [128][64]
    unsigned short* W2t  = W1t  + 64 * 128;                // [128][128]
    unsigned short* Wu1t = W2t  + 128 * 128;               // [128][256]
    unsigned short* Wu2t = Wu1t + 256 * 128;               // [128][256]
    unsigned short* bufA = Wu2t + 256 * 128;               // [ROWS][128] bf16
    unsigned short* bufB = bufA + (size_t)ROWS * HID;
    unsigned short* bufC = bufB + (size_t)ROWS * HID;
    unsigned short* bufD = bufC + (size_t)ROWS * HID;

    const size_t need4 = (size_t)(90112) * 2 + 4 * (size_t)ROWS * HID * 2;
    const bool big = ws_size >= need4;

    dim3 b256(256), b512(512);

    wconv_all<<<352, b256, 0, stream>>>(W1, W2, Wu1, Wu2, W1t, W2t, Wu1t, Wu2t);

    // layer-1 embeddings: SE1 -> bufA, IE1 -> bufB (one launch)
    embed_mfma<64, true><<<2500, b256, 0, stream>>>(state, internal, W1t, b1, bufA, bufB);

    // hu1 = relu([aggr1 | IE1] @ Wu1 + bu1) -> f32 d_out + bf16 bufC
    update_mfma<<<8 * 313, b512, 0, stream>>>(bufA, bufB, sidx, iidx, Wu1t, bu1, hu1, bufC, 1);

    if (big) {
        // se2: bufA -> bufB; ie2: bufC -> bufD (single launch, disjoint buffers)
        embed_mfma<128, false><<<2500, b256, 0, stream>>>(bufA, bufC, W2t, b2, bufB, bufD);
        update_mfma<<<8 * 313, b512, 0, stream>>>(bufB, bufD, sidx, iidx, Wu2t, bu2, hu2, nullptr, 0);
    } else {
        // sequential fallback (3 buffers)
        embed_mfma<128, false><<<1250, b256, 0, stream>>>(bufA, nullptr, W2t, b2, bufB, nullptr);
        embed_mfma<128, false><<<1250, b256, 0, stream>>>(bufC, nullptr, W2t, b2, bufA, nullptr);
        update_mfma<<<8 * 313, b512, 0, stream>>>(bufB, bufA, sidx, iidx, Wu2t, bu2, hu2, nullptr, 0);
    }
}